// Round 1
// 393.673 us; speedup vs baseline: 1.0578x; 1.0578x over previous
//
#include <hip/hip_runtime.h>

// out[b,s,:] = (emb[x[b,s],:] @ W + b) * sqrt(2048)
// x:[4,8192] int32, emb:[50000,300] fp32, W:[300,2048] fp32, b:[2048] fp32
// out: [4,8192,2048] fp32.  M=32768 tokens, N=2048, K=300 (padded 320).
//
// R5 plan: kill the staging bottleneck.
//  - prep_emb: emb fp32 -> embh fp16 [50000][320] ONCE (was re-converted 16x per
//    token row inside the K-loop). A-side L2 working set 4.9MB->2.5MB per XCD.
//  - prep_wsw: W -> per-(ntile,kc) 16KB tiles, pre-transposed AND pre-XOR-swizzled,
//    so the GEMM's B stage is a linear async copy.
//  - embed_gemm: stage A and B with global_load_lds_dwordx4 (async, no VGPR round
//    trip, no cvt). Swizzle lives in the per-lane GLOBAL source address; LDS dest
//    is linear (rule: both-sides-or-neither).  LDS layout/read side unchanged:
//    chunk c of row r at r*64 + (c^(r&7))*8 halves -> b128 reads conflict-free.

#define VOCAB 50000
#define TOKENS 32768
#define EMB 300
#define DM 2048
#define KPAD 320
#define SCALE 45.25483399593904f

typedef _Float16 f16;
typedef _Float16 h4 __attribute__((ext_vector_type(4)));
typedef _Float16 h8 __attribute__((ext_vector_type(8)));
typedef float f32x4 __attribute__((ext_vector_type(4)));

__device__ __forceinline__ void gload_lds16(const f16* g, f16* l) {
    __builtin_amdgcn_global_load_lds(
        (const __attribute__((address_space(1))) void*)g,
        (__attribute__((address_space(3))) void*)l, 16, 0, 0);
}

// ---- prep: embh[row][k] = (f16)emb[row][k], k zero-padded 300->320 ----
__global__ __launch_bounds__(256) void prep_emb(const float* __restrict__ emb,
                                                f16* __restrict__ embh) {
    int idx = blockIdx.x * 256 + threadIdx.x;      // one 8-half chunk each; VOCAB*40 total
    if (idx >= VOCAB * 40) return;
    int row = idx / 40;
    int c = idx - row * 40;
    h8 hv = {};
    const float* src = emb + (size_t)row * EMB + (c << 3);
    if (c < 37) {
        float4 a = *(const float4*)src;
        float4 d = *(const float4*)(src + 4);
        hv[0]=(f16)a.x; hv[1]=(f16)a.y; hv[2]=(f16)a.z; hv[3]=(f16)a.w;
        hv[4]=(f16)d.x; hv[5]=(f16)d.y; hv[6]=(f16)d.z; hv[7]=(f16)d.w;
    } else if (c == 37) {                           // k = 296..303: only 296..299 valid
        float4 a = *(const float4*)src;
        hv[0]=(f16)a.x; hv[1]=(f16)a.y; hv[2]=(f16)a.z; hv[3]=(f16)a.w;
    }                                               // c = 38,39: zeros
    *(h8*)(embh + (size_t)row * KPAD + (c << 3)) = hv;
}

// ---- prep: Wsw[(ntile*5+kc)*1024 + p] = 8 halves of W-column, pre-swizzled ----
// position p = row*8 + cpos holds LOGICAL chunk (cpos ^ (row&7)) of B-row
// n = ntile*128+row, chunk kc  ->  GEMM stages it with a LINEAR global_load_lds.
__global__ __launch_bounds__(256) void prep_wsw(const float* __restrict__ W,
                                                f16* __restrict__ Wsw) {
    int idx = blockIdx.x * 256 + threadIdx.x;      // 16*5*1024 = 81920 chunks
    int p = idx & 1023;
    int tile = idx >> 10;                          // ntile*5 + kc
    int kc = tile % 5;
    int ntile = tile / 5;
    int row = p >> 3, cpos = p & 7;
    int clog = cpos ^ (row & 7);
    int n = (ntile << 7) + row;
    int kbase = (kc << 6) + (clog << 3);
    h8 hv = {};
    #pragma unroll
    for (int j = 0; j < 8; ++j) {
        int k = kbase + j;
        if (k < EMB) hv[j] = (f16)W[(size_t)k * DM + n];
    }
    *(h8*)(Wsw + (size_t)idx * 8) = hv;
}

__global__ __launch_bounds__(256) void prep_b(const float* __restrict__ b, float* __restrict__ bs) {
    int i = blockIdx.x * 256 + threadIdx.x;
    if (i < DM) bs[i] = b[i] * SCALE;
}

// ---- main GEMM: 128x128 tile, BK=64 x 5 chunks, 4 waves 2x2, 4x4 MFMA 16x16x32 ----
// All staging via global_load_lds (async). Per thread per chunk: 8 issue instrs.
__global__ __launch_bounds__(256, 4) void embed_gemm(
        const int* __restrict__ x, const f16* __restrict__ embh,
        const f16* __restrict__ Wsw, const float* __restrict__ bs,
        float* __restrict__ out)
{
    __shared__ __align__(16) f16 As[128 * 64];
    __shared__ __align__(16) f16 Bs[128 * 64];
    __shared__ int toks[128];

    // XCD-aware remap: all 16 N-tiles of an M-tile run consecutively on one XCD,
    // so the gathered A rows (77 KB fp16) + Wsw (1.3 MB) stay in that XCD's 4MB L2.
    const int lin  = blockIdx.x;           // 0..4095
    const int xcd  = lin & 7;
    const int slot = lin >> 3;             // 0..511 within XCD
    const int mtile = (xcd << 5) + (slot >> 4);   // 32 M-tiles per XCD
    const int ntile = slot & 15;
    const int m0 = mtile << 7;
    const int n0 = ntile << 7;

    const int t = threadIdx.x;
    const int lane = t & 63;
    const int wave = t >> 6;
    const int wm = (wave >> 1) << 6;
    const int wn = (wave & 1) << 6;
    const int quad = lane >> 4;
    const int lr = lane & 15;

    if (t < 128) toks[t] = x[m0 + t];
    __syncthreads();

    // A gather sources, hoisted: thread t serves chunk p = i*256+t, i=0..3
    //   row = i*32 + (t>>3), cpos = t&7; source = logical chunk cpos^(row&7).
    //   (i*32 ≡ 0 mod 8, so row&7 and hence the XOR are i-invariant.)
    const int arow_lo = t >> 3;
    const int axor = ((t & 7) ^ (arow_lo & 7)) << 3;   // halves
    const f16* asrc[4];
    #pragma unroll
    for (int i = 0; i < 4; ++i)
        asrc[i] = embh + (size_t)toks[(i << 5) + arow_lo] * KPAD + axor;

    // B source: tile-contiguous, already swizzled -> purely linear copy
    const f16* bsrc = Wsw + (size_t)ntile * 40960 + ((size_t)t << 3);

    f16* adst = As + (t << 3);             // per-lane dest, linear (lane*16B)
    f16* bdst = Bs + (t << 3);

    f32x4 acc[4][4] = {};

    for (int kc = 0; kc < 5; ++kc) {
        const int koff = kc << 6;          // halves into a row
        #pragma unroll
        for (int i = 0; i < 4; ++i)
            gload_lds16(bsrc + (kc << 13) + (i << 11), bdst + (i << 11));
        #pragma unroll
        for (int i = 0; i < 4; ++i)
            gload_lds16(asrc[i] + koff, adst + (i << 11));
        __syncthreads();                   // compiler drains vmcnt before barrier

        #pragma unroll
        for (int kk = 0; kk < 2; ++kk) {
            h8 af[4], bfr[4];
            const int c = (kk << 2) + quad;
            #pragma unroll
            for (int mi = 0; mi < 4; ++mi) {
                int m = wm + (mi << 4) + lr;
                af[mi] = *(const h8*)(As + (m << 6) + ((c ^ (m & 7)) << 3));
            }
            #pragma unroll
            for (int ni = 0; ni < 4; ++ni) {
                int n = wn + (ni << 4) + lr;
                bfr[ni] = *(const h8*)(Bs + (n << 6) + ((c ^ (n & 7)) << 3));
            }
            #pragma unroll
            for (int mi = 0; mi < 4; ++mi)
                #pragma unroll
                for (int ni = 0; ni < 4; ++ni)
                    acc[mi][ni] = __builtin_amdgcn_mfma_f32_16x16x32_f16(
                        af[mi], bfr[ni], acc[mi][ni], 0, 0, 0);
        }
        __syncthreads();
    }

    // epilogue: C/D layout col=lane&15, row=quad*4+r
    #pragma unroll
    for (int ni = 0; ni < 4; ++ni) {
        int n = n0 + wn + (ni << 4) + lr;
        float bias = bs[n];
        #pragma unroll
        for (int mi = 0; mi < 4; ++mi) {
            int mb = m0 + wm + (mi << 4) + (quad << 2);
            #pragma unroll
            for (int r = 0; r < 4; ++r) {
                out[(size_t)(mb + r) * DM + n] = fmaf(acc[mi][ni][r], SCALE, bias);
            }
        }
    }
}

// ================== fallback tier: previous-round kernel (small ws) ==================
__global__ __launch_bounds__(256) void prep_w_old(const float* __restrict__ W, f16* __restrict__ Wt) {
    __shared__ f16 tile[64 * 68];
    const int k0 = blockIdx.x << 6;
    const int n0 = blockIdx.y << 6;
    const int t = threadIdx.x;
    #pragma unroll
    for (int i = 0; i < 4; ++i) {
        int idx = (i << 8) + t;
        int kr = idx >> 4;
        int nc = idx & 15;
        h4 hv = {};
        if (k0 + kr < EMB) {
            float4 v = *(const float4*)(W + (size_t)(k0 + kr) * DM + n0 + (nc << 2));
            hv[0]=(f16)v.x; hv[1]=(f16)v.y; hv[2]=(f16)v.z; hv[3]=(f16)v.w;
        }
        *(h4*)(tile + kr * 68 + (nc << 2)) = hv;
    }
    __syncthreads();
    #pragma unroll
    for (int i = 0; i < 4; ++i) {
        int idx = (i << 8) + t;
        int n  = idx >> 4;
        int kc = idx & 15;
        h4 hv;
        hv[0] = tile[(kc * 4 + 0) * 68 + n];
        hv[1] = tile[(kc * 4 + 1) * 68 + n];
        hv[2] = tile[(kc * 4 + 2) * 68 + n];
        hv[3] = tile[(kc * 4 + 3) * 68 + n];
        *(h4*)(Wt + (size_t)(n0 + n) * KPAD + k0 + (kc << 2)) = hv;
    }
}

__global__ __launch_bounds__(256, 4) void embed_gemm_old(
        const int* __restrict__ x, const float* __restrict__ emb,
        const f16* __restrict__ Wt, const float* __restrict__ bs,
        float* __restrict__ out)
{
    __shared__ __align__(16) f16 As[128 * 64];
    __shared__ __align__(16) f16 Bs[128 * 64];
    __shared__ int toks[128];

    const int lin  = blockIdx.x;
    const int xcd  = lin & 7;
    const int slot = lin >> 3;
    const int mtile = (xcd << 5) + (slot >> 4);
    const int ntile = slot & 15;
    const int m0 = mtile << 7;
    const int n0 = ntile << 7;

    const int t = threadIdx.x;
    const int lane = t & 63;
    const int wave = t >> 6;
    const int wm = (wave >> 1) << 6;
    const int wn = (wave & 1) << 6;
    const int quad = lane >> 4;
    const int lr = lane & 15;

    if (t < 128) toks[t] = x[m0 + t];
    __syncthreads();

    f32x4 acc[4][4] = {};

    for (int kc = 0; kc < 5; ++kc) {
        const int k0 = kc << 6;
        #pragma unroll
        for (int i = 0; i < 4; ++i) {
            int idx = (i << 8) + t;
            int row = idx >> 3;
            int c   = idx & 7;
            h8 v = *(const h8*)(Wt + (size_t)(n0 + row) * KPAD + k0 + (c << 3));
            *(h8*)(Bs + (row << 6) + ((c ^ (row & 7)) << 3)) = v;
        }
        #pragma unroll
        for (int i = 0; i < 8; ++i) {
            int q   = (i << 8) + t;
            int row = q >> 4;
            int qc  = q & 15;
            int k   = k0 + (qc << 2);
            h4 hv = {};
            if (k + 3 < EMB) {
                float4 v = *(const float4*)(emb + (size_t)toks[row] * EMB + k);
                hv[0]=(f16)v.x; hv[1]=(f16)v.y; hv[2]=(f16)v.z; hv[3]=(f16)v.w;
            }
            int c = qc >> 1, half = qc & 1;
            *(h4*)(As + (row << 6) + (((c ^ (row & 7)) << 3) + (half << 2))) = hv;
        }
        __syncthreads();

        #pragma unroll
        for (int kk = 0; kk < 2; ++kk) {
            h8 af[4], bfr[4];
            const int c = (kk << 2) + quad;
            #pragma unroll
            for (int mi = 0; mi < 4; ++mi) {
                int m = wm + (mi << 4) + lr;
                af[mi] = *(const h8*)(As + (m << 6) + ((c ^ (m & 7)) << 3));
            }
            #pragma unroll
            for (int ni = 0; ni < 4; ++ni) {
                int n = wn + (ni << 4) + lr;
                bfr[ni] = *(const h8*)(Bs + (n << 6) + ((c ^ (n & 7)) << 3));
            }
            #pragma unroll
            for (int mi = 0; mi < 4; ++mi)
                #pragma unroll
                for (int ni = 0; ni < 4; ++ni)
                    acc[mi][ni] = __builtin_amdgcn_mfma_f32_16x16x32_f16(
                        af[mi], bfr[ni], acc[mi][ni], 0, 0, 0);
        }
        __syncthreads();
    }

    #pragma unroll
    for (int ni = 0; ni < 4; ++ni) {
        int n = n0 + wn + (ni << 4) + lr;
        float bias = bs[n];
        #pragma unroll
        for (int mi = 0; mi < 4; ++mi) {
            int mb = m0 + wm + (mi << 4) + (quad << 2);
            #pragma unroll
            for (int r = 0; r < 4; ++r) {
                out[(size_t)(mb + r) * DM + n] = fmaf(acc[mi][ni][r], SCALE, bias);
            }
        }
    }
}

// ---- correct-but-slow fp32 fallback if ws is too small ----
__global__ __launch_bounds__(256) void naive_kernel(
        const int* __restrict__ x, const float* __restrict__ emb,
        const float* __restrict__ W, const float* __restrict__ b, float* __restrict__ out)
{
    size_t idx = (size_t)blockIdx.x * 256 + threadIdx.x;
    int n = (int)(idx & (DM - 1));
    size_t m = idx >> 11;
    const float* e = emb + (size_t)x[m] * EMB;
    float a = 0.f;
    for (int k = 0; k < EMB; ++k) a = fmaf(e[k], W[(size_t)k * DM + n], a);
    out[idx] = (a + b[n]) * SCALE;
}

extern "C" void kernel_launch(void* const* d_in, const int* in_sizes, int n_in,
                              void* d_out, int out_size, void* d_ws, size_t ws_size,
                              hipStream_t stream) {
    const int*   x   = (const int*)d_in[0];
    const float* emb = (const float*)d_in[1];
    const float* W   = (const float*)d_in[2];
    const float* b   = (const float*)d_in[3];
    float* out = (float*)d_out;

    const size_t embh_bytes = (size_t)VOCAB * KPAD * sizeof(f16);  // 32,000,000
    const size_t wsw_bytes  = (size_t)DM * KPAD * sizeof(f16);     //  1,310,720
    const size_t need_big   = embh_bytes + wsw_bytes + (size_t)DM * sizeof(float);
    const size_t need_small = wsw_bytes + (size_t)DM * sizeof(float);

    if (ws_size >= need_big) {
        f16* embh = (f16*)d_ws;
        f16* Wsw  = (f16*)((char*)d_ws + embh_bytes);
        float* bsp = (float*)((char*)d_ws + embh_bytes + wsw_bytes);
        prep_emb<<<(VOCAB * 40 + 255) / 256, 256, 0, stream>>>(emb, embh);
        prep_wsw<<<(16 * 5 * 1024) / 256, 256, 0, stream>>>(W, Wsw);
        prep_b<<<DM / 256, 256, 0, stream>>>(b, bsp);
        embed_gemm<<<(TOKENS / 128) * (DM / 128), 256, 0, stream>>>(x, embh, Wsw, bsp, out);
    } else if (ws_size >= need_small) {
        f16* Wt = (f16*)d_ws;
        float* bsp = (float*)((char*)d_ws + wsw_bytes);
        prep_w_old<<<dim3(KPAD / 64, DM / 64), 256, 0, stream>>>(W, Wt);
        prep_b<<<DM / 256, 256, 0, stream>>>(b, bsp);
        embed_gemm_old<<<(TOKENS / 128) * (DM / 128), 256, 0, stream>>>(x, emb, Wt, bsp, out);
    } else {
        naive_kernel<<<((size_t)TOKENS * DM) / 256, 256, 0, stream>>>(x, emb, W, b, out);
    }
}